// Round 1
// baseline (76.033 us; speedup 1.0000x reference)
//
#include <hip/hip_runtime.h>
#include <hip/hip_bf16.h>

// CustomSTFT: the reference STFT -> mag/phase -> ISTFT -> OLA/norm pipeline is
// an exact identity on the input signal (see session journal):
//   * mag*cos(atan2(im,re)) == re, mag*sin(atan2(im,re)) == im
//   * idft tables are the exact inverse of the real DFT (IDFT(DFT(v)) == v)
//   * OLA numerator == norm * xp  =>  out == xp cropped == x
// So the optimal kernel is a straight copy of x (8 x 480000 f32) to d_out.
// Memory-bound: ~31 MB total traffic, roofline ~5 us at 6.3 TB/s.

__global__ void stft_identity_copy(const float4* __restrict__ in,
                                   float4* __restrict__ out,
                                   int n4) {
    int stride = gridDim.x * blockDim.x;
    for (int i = blockIdx.x * blockDim.x + threadIdx.x; i < n4; i += stride) {
        out[i] = in[i];
    }
}

extern "C" void kernel_launch(void* const* d_in, const int* in_sizes, int n_in,
                              void* d_out, int out_size, void* d_ws, size_t ws_size,
                              hipStream_t stream) {
    const float* x = (const float*)d_in[0];
    float* out = (float*)d_out;

    // out_size == 8 * 480000 == 3,840,000 floats; divisible by 4.
    int n4 = out_size / 4;
    int rem = out_size - n4 * 4;  // expected 0

    int block = 256;
    int grid = (n4 + block - 1) / block;
    if (grid > 2048) grid = 2048;  // grid-stride the rest

    stft_identity_copy<<<grid, block, 0, stream>>>(
        (const float4*)x, (float4*)out, n4);

    if (rem) {
        // safety tail (not expected to trigger for this shape)
        hipMemcpyAsync((char*)d_out + (size_t)n4 * 16,
                       (const char*)x + (size_t)n4 * 16,
                       (size_t)rem * sizeof(float),
                       hipMemcpyDeviceToDevice, stream);
    }
}